// Round 9
// baseline (128.650 us; speedup 1.0000x reference)
//
#include <hip/hip_runtime.h>
#include <stdint.h>
#include <stddef.h>

// Actor_DeepSet: rows = 131072 (= 16384 batches x 8 agents), OBS=64, HIDDEN=128, OUT=16.
// R9: zero-barrier redesign. One wave (64 thr) per 16 rows (2 batches); ALL
//     phases wave-private (layer2: A = own 16 rows, B = all 128 w2 cols
//     streamed from L2) -> no __syncthreads at all. Single 8192B LDS pool:
//     Xs / Hc(XOR-swz) / H2 alias via in-wave DS ordering. Register phases
//     forced <=~95: layer1 split into two 4-col phases (unroll 1), layer2
//     pre-loads all A-frags then streams w2. __launch_bounds__(64,4) ->
//     16 waves/CU (LDS allows 19).

typedef __attribute__((ext_vector_type(8))) short short8;       // 8 x bf16 (4 VGPR)
typedef __attribute__((ext_vector_type(4))) float floatx4;      // MFMA C/D
typedef __attribute__((ext_vector_type(4))) unsigned int uintx4;
typedef __attribute__((ext_vector_type(4))) float float4v;

static __device__ __forceinline__ unsigned int cvtpk(float lo, float hi) {
    unsigned int r;
    asm("v_cvt_pk_bf16_f32 %0, %1, %2" : "=v"(r) : "v"(lo), "v"(hi));
    return r;
}
static __device__ __forceinline__ unsigned short f2bf(float f) {
    return (unsigned short)cvtpk(f, f);
}
static __device__ __forceinline__ floatx4 mfma16(short8 a, short8 b, floatx4 c) {
    return __builtin_amdgcn_mfma_f32_16x16x32_bf16(a, b, c, 0, 0, 0);
}

// ushort indices into the 8192-B pool P[4096]:
// Xs: [16][72] plain          (2304 B, lifetime: stage -> window loads)
// Hc: [16][256] XOR-swizzled  (8192 B, lifetime: kx/h1 writes -> layer2 A-reads)
// H2: [16][128] XOR-swizzled  (4096 B, lifetime: layer2 writes -> final reads)
#define XSI(r, c) ((r) * 72 + (c))
#define HCI(r, c) (((((r) << 5) | ((c) >> 3)) ^ ((r) & 7)) * 8 + ((c) & 7))
#define H2I(r, c) (((((r) << 4) | ((c) >> 3)) ^ ((r) & 7)) * 8 + ((c) & 7))

// ---- prologue: convert all weights to bf16 into d_ws (w1o pre-scaled by 1/8) ----
// ws layout (ushort elems): w1[8192] | w1o[8192] | w2[32768] | wv[2048]  (total 51200)
__global__ void cvt_weights(const float* __restrict__ w1, const float* __restrict__ w1o,
                            const float* __restrict__ w2, const float* __restrict__ wv,
                            unsigned short* __restrict__ ws) {
    int i = blockIdx.x * 256 + threadIdx.x;   // grid sized exactly 51200/256 = 200 blocks
    float v;
    if (i < 8192)       v = w1[i];
    else if (i < 16384) v = w1o[i - 8192] * 0.125f;   // fold the /8 (relu pos-homog.)
    else if (i < 49152) v = w2[i - 16384];
    else                v = wv[i - 49152];
    ws[i] = f2bf(v);
}

__launch_bounds__(64, 4)
__global__ void actor_fused(const float* __restrict__ X,          // [131072][64]
                            const unsigned short* __restrict__ ws,
                            const float* __restrict__ b1p,        // [128]
                            const float* __restrict__ b1op,       // [128]
                            const float* __restrict__ b2p,        // [128]
                            const float* __restrict__ bvp,        // [16]
                            float* __restrict__ out) {            // [131072][16]
    __shared__ __align__(16) unsigned short P[4096];   // 8192 B

    const int lane = threadIdx.x;      // block = 1 wave
    const int l15  = lane & 15;
    const int l16  = lane >> 4;        // 0..3
    const long R0  = (long)blockIdx.x * 16;   // 16 rows (= 2 batches) per wave

    const unsigned short* w1b  = ws;
    const unsigned short* w1ob = ws + 8192;
    const unsigned short* w2b  = ws + 16384;
    const unsigned short* wvb  = ws + 49152;

    // --- stage own 16 rows: X f32 -> bf16 Xs (coalesced: lane l covers 64 B) ---
    {
        const int r = lane >> 2, q = lane & 3;
        const float4v* src = (const float4v*)(X + (R0 + r) * 64 + q * 16);
        const float4v f0 = src[0], f1 = src[1], f2 = src[2], f3 = src[3];
        uintx4 lo, hi;
        lo.x = cvtpk(f0.x, f0.y); lo.y = cvtpk(f0.z, f0.w);
        lo.z = cvtpk(f1.x, f1.y); lo.w = cvtpk(f1.z, f1.w);
        hi.x = cvtpk(f2.x, f2.y); hi.y = cvtpk(f2.z, f2.w);
        hi.z = cvtpk(f3.x, f3.y); hi.w = cvtpk(f3.z, f3.w);
        *(uintx4*)(&P[XSI(r, q * 16)])     = lo;
        *(uintx4*)(&P[XSI(r, q * 16 + 8)]) = hi;
        if (q == 0) *(uintx4*)(&P[XSI(r, 64)]) = lo;   // wrap: elems 0..7 -> 64..71
    }
    // no barrier: compiler emits lgkmcnt wait before the dependent reads below.

    // --- per-lane A windows (row l15 of own tile), loaded ONCE ---
    uintx4 v0lo = *(const uintx4*)(&P[XSI(l15, l16 * 8)]);
    uintx4 v0hi = *(const uintx4*)(&P[XSI(l15, l16 * 8 + 8)]);
    uintx4 v1lo = *(const uintx4*)(&P[XSI(l15, 32 + l16 * 8)]);
    uintx4 v1hi = *(const uintx4*)(&P[XSI(l15, 40 + l16 * 8)]);
    unsigned int u0[8] = {v0lo.x, v0lo.y, v0lo.z, v0lo.w, v0hi.x, v0hi.y, v0hi.z, v0hi.w};
    unsigned int u1[8] = {v1lo.x, v1lo.y, v1lo.z, v1lo.w, v1hi.x, v1hi.y, v1hi.z, v1hi.w};
    // Xs region is dead once u0/u1 are in regs; Hc writes below may overwrite it
    // (in-wave DS ops execute in program order; reads completed before writes issue).

    // --- layer1 "other": 8 rolled passes, split into two 4-col phases (regs) ---
    // S_{a=kx}[h] = sum_{j!=a'} relu( roll_{kx+1}(x_j) . (w1o/8)[h] + b1o/8 )
    #pragma unroll 1
    for (int ph = 0; ph < 2; ++ph) {
        short8 bw[4][2];
        float  bia[4];
        #pragma unroll
        for (int i = 0; i < 4; ++i) {
            const int h = (ph * 4 + i) * 16 + l15;
            bw[i][0] = *(const short8*)(w1ob + h * 64 + l16 * 8);
            bw[i][1] = *(const short8*)(w1ob + h * 64 + 32 + l16 * 8);
            bia[i]   = 0.125f * b1op[h];
        }
        #pragma unroll
        for (int kx = 0; kx < 8; ++kx) {
            const int kk = kx + 1;          // compile-time roll per unrolled iter
            const int c  = kk >> 1;
            union { unsigned int u[4]; short8 v; } A0, A1;
            #pragma unroll
            for (int d = 0; d < 4; ++d) {
                if (kk & 1) {
                    A0.u[d] = (u0[d + c] >> 16) | (u0[d + c + 1] << 16);
                    A1.u[d] = (u1[d + c] >> 16) | (u1[d + c + 1] << 16);
                } else {
                    A0.u[d] = u0[d + c];
                    A1.u[d] = u1[d + c];
                }
            }
            floatx4 acc[4];
            #pragma unroll
            for (int i = 0; i < 4; ++i) {
                const float b = bia[i];
                acc[i] = (floatx4){b, b, b, b};
            }
            #pragma unroll
            for (int i = 0; i < 4; ++i) {
                acc[i] = mfma16(A0.v, bw[i][0], acc[i]);
                acc[i] = mfma16(A1.v, bw[i][1], acc[i]);
            }
            // epilogue: relu, sum rows j!=first of each batch, store to Hc S-half
            #pragma unroll
            for (int i = 0; i < 4; ++i) {
                float r0 = fmaxf(acc[i].x, 0.f);
                float r1 = fmaxf(acc[i].y, 0.f);
                float r2 = fmaxf(acc[i].z, 0.f);
                float r3 = fmaxf(acc[i].w, 0.f);
                float t = r1 + r2 + r3 + (((l16 & 1) != 0) ? r0 : 0.f);
                float s = t + __shfl_xor(t, 16, 64);
                if ((lane & 16) == 0) {
                    int row = ((lane >> 5) << 3) + kx;          // local row (batch,agent)
                    P[HCI(row, 128 + (ph * 4 + i) * 16 + l15)] = f2bf(s);
                }
            }
        }
    }

    // --- layer1 self (w1, roll 0): two 4-col phases ---
    #pragma unroll 1
    for (int ph = 0; ph < 2; ++ph) {
        short8 bw[4][2];
        float  bia[4];
        #pragma unroll
        for (int i = 0; i < 4; ++i) {
            const int h = (ph * 4 + i) * 16 + l15;
            bw[i][0] = *(const short8*)(w1b + h * 64 + l16 * 8);
            bw[i][1] = *(const short8*)(w1b + h * 64 + 32 + l16 * 8);
            bia[i]   = b1p[h];
        }
        union { unsigned int u[4]; short8 v; } A0, A1;
        #pragma unroll
        for (int d = 0; d < 4; ++d) { A0.u[d] = u0[d]; A1.u[d] = u1[d]; }
        floatx4 acc[4];
        #pragma unroll
        for (int i = 0; i < 4; ++i) {
            const float b = bia[i];
            acc[i] = (floatx4){b, b, b, b};
        }
        #pragma unroll
        for (int i = 0; i < 4; ++i) {
            acc[i] = mfma16(A0.v, bw[i][0], acc[i]);
            acc[i] = mfma16(A1.v, bw[i][1], acc[i]);
        }
        #pragma unroll
        for (int i = 0; i < 4; ++i) {
            #pragma unroll
            for (int r = 0; r < 4; ++r) {
                P[HCI(l16 * 4 + r, (ph * 4 + i) * 16 + l15)] = f2bf(fmaxf(acc[i][r], 0.f));
            }
        }
    }

    // --- layer2: h2 = relu(Hcat @ w2^T + b2), A = own 16 rows, B = ALL 128 cols.
    //     Pre-read all 8 A-frags (32 VGPR) so Hc is dead before H2 overwrites it. ---
    short8 af[8];
    #pragma unroll
    for (int s = 0; s < 8; ++s)
        af[s] = *(const short8*)(&P[HCI(l15, s * 32 + l16 * 8)]);

    #pragma unroll 1
    for (int ng = 0; ng < 4; ++ng) {
        const int n0 = 2 * ng, n1 = 2 * ng + 1;
        const float bb0 = b2p[n0 * 16 + l15];
        const float bb1 = b2p[n1 * 16 + l15];
        floatx4 a0 = (floatx4){bb0, bb0, bb0, bb0};
        floatx4 a1 = (floatx4){bb1, bb1, bb1, bb1};
        #pragma unroll
        for (int s = 0; s < 8; ++s) {
            short8 w0 = *(const short8*)(w2b + (size_t)(n0 * 16 + l15) * 256 + s * 32 + l16 * 8);
            short8 w1f = *(const short8*)(w2b + (size_t)(n1 * 16 + l15) * 256 + s * 32 + l16 * 8);
            a0 = mfma16(af[s], w0, a0);
            a1 = mfma16(af[s], w1f, a1);
        }
        // H2 writes (alias over Hc — all Hc reads already done via af[])
        #pragma unroll
        for (int r = 0; r < 4; ++r) {
            P[H2I(l16 * 4 + r, n0 * 16 + l15)] = f2bf(fmaxf(a0[r], 0.f));
            P[H2I(l16 * 4 + r, n1 * 16 + l15)] = f2bf(fmaxf(a1[r], 0.f));
        }
    }

    // --- final layer: out = h2 @ wv^T + bv (own 16 rows) ---
    short8 wvf[4];
    #pragma unroll
    for (int s = 0; s < 4; ++s)
        wvf[s] = *(const short8*)(wvb + l15 * 128 + s * 32 + l16 * 8);
    const float bv_r = bvp[l15];

    {
        floatx4 acc4 = (floatx4){bv_r, bv_r, bv_r, bv_r};
        #pragma unroll
        for (int s = 0; s < 4; ++s) {
            short8 a = *(const short8*)(&P[H2I(l15, s * 32 + l16 * 8)]);
            acc4 = mfma16(a, wvf[s], acc4);
        }
        #pragma unroll
        for (int r = 0; r < 4; ++r) {
            long row = R0 + l16 * 4 + r;
            out[row * 16 + l15] = acc4[r];
        }
    }
}

extern "C" void kernel_launch(void* const* d_in, const int* in_sizes, int n_in,
                              void* d_out, int out_size, void* d_ws, size_t ws_size,
                              hipStream_t stream) {
    (void)n_in; (void)out_size; (void)ws_size;
    const float* X   = (const float*)d_in[0];
    const float* w1  = (const float*)d_in[1];
    const float* b1  = (const float*)d_in[2];
    const float* w1o = (const float*)d_in[3];
    const float* b1o = (const float*)d_in[4];
    const float* w2  = (const float*)d_in[5];
    const float* b2  = (const float*)d_in[6];
    const float* wv  = (const float*)d_in[7];
    const float* bv  = (const float*)d_in[8];
    float* out = (float*)d_out;
    unsigned short* ws = (unsigned short*)d_ws;

    // weights -> bf16 (51200 elems, 200*256 threads exactly)
    cvt_weights<<<200, 256, 0, stream>>>(w1, w1o, w2, wv, ws);

    const int rows   = in_sizes[0] / 64;   // 131072
    const int blocks = rows / 16;          // 8192 one-wave blocks
    actor_fused<<<blocks, 64, 0, stream>>>(X, ws, b1, b1o, b2, bv, out);
}